// Round 1
// baseline (320.018 us; speedup 1.0000x reference)
//
#include <hip/hip_runtime.h>
#include <stdint.h>

#define B_ROWS 8192
#define INP    1024
#define HID    1024
#define MEMD   256
#define KIN    2304   // INP+HID+MEMD
#define KHM    1280   // HID+MEMD
#define NCAT   144    // 136 outputs padded to 144

typedef unsigned short u16;
typedef unsigned int   u32;
typedef __attribute__((ext_vector_type(8))) short bf16x8;
typedef __attribute__((ext_vector_type(4))) float f32x4;

__device__ __forceinline__ u16 f2bf(float f) {
  u32 b = __builtin_bit_cast(u32, f);
  u32 r = b + 0x7FFF + ((b >> 16) & 1);   // RNE
  return (u16)(r >> 16);
}

__device__ __forceinline__ void gload16(const void* g, void* l) {
  __builtin_amdgcn_global_load_lds(
      (const __attribute__((address_space(1))) u32*)g,
      (__attribute__((address_space(3))) u32*)l, 16, 0, 0);
}

// ---- converters --------------------------------------------------------
__global__ void k_cvt_xh(const float* __restrict__ x, const float* __restrict__ h0,
                         u16* __restrict__ Abig) {
  const int nIter = B_ROWS * 2048 / 8;  // 2,097,152 groups of 8
  for (int i = blockIdx.x * blockDim.x + threadIdx.x; i < nIter;
       i += gridDim.x * blockDim.x) {
    int row = i >> 8;             // 256 groups per row
    int col = (i & 255) * 8;
    const float* src = (col < 1024) ? (x + (size_t)row * 1024 + col)
                                    : (h0 + (size_t)row * 1024 + (col - 1024));
    float4 v0 = ((const float4*)src)[0];
    float4 v1 = ((const float4*)src)[1];
    union { u16 u[8]; uint4 q; } pk;
    pk.u[0]=f2bf(v0.x); pk.u[1]=f2bf(v0.y); pk.u[2]=f2bf(v0.z); pk.u[3]=f2bf(v0.w);
    pk.u[4]=f2bf(v1.x); pk.u[5]=f2bf(v1.y); pk.u[6]=f2bf(v1.z); pk.u[7]=f2bf(v1.w);
    *((uint4*)(Abig + (size_t)row * KIN + col)) = pk.q;
  }
}

__global__ void k_cvt_mem(const float* __restrict__ mem,
                          u16* __restrict__ Abig, u16* __restrict__ hm) {
  int i = blockIdx.x * blockDim.x + threadIdx.x;  // 262,144 threads exactly
  int row = i >> 5;
  int col = (i & 31) * 8;
  const float* src = mem + (size_t)row * MEMD + col;
  float4 v0 = ((const float4*)src)[0];
  float4 v1 = ((const float4*)src)[1];
  union { u16 u[8]; uint4 q; } pk;
  pk.u[0]=f2bf(v0.x); pk.u[1]=f2bf(v0.y); pk.u[2]=f2bf(v0.z); pk.u[3]=f2bf(v0.w);
  pk.u[4]=f2bf(v1.x); pk.u[5]=f2bf(v1.y); pk.u[6]=f2bf(v1.z); pk.u[7]=f2bf(v1.w);
  *((uint4*)(Abig + (size_t)row * KIN + 2048 + col)) = pk.q;
  *((uint4*)(hm   + (size_t)row * KHM + 1024 + col)) = pk.q;
}

__global__ void k_cvt_wh(const float* __restrict__ Wh, u16* __restrict__ WhB) {
  int i = blockIdx.x * blockDim.x + threadIdx.x;  // 294,912 threads exactly
  const float* src = Wh + (size_t)i * 8;
  float4 v0 = ((const float4*)src)[0];
  float4 v1 = ((const float4*)src)[1];
  union { u16 u[8]; uint4 q; } pk;
  pk.u[0]=f2bf(v0.x); pk.u[1]=f2bf(v0.y); pk.u[2]=f2bf(v0.z); pk.u[3]=f2bf(v0.w);
  pk.u[4]=f2bf(v1.x); pk.u[5]=f2bf(v1.y); pk.u[6]=f2bf(v1.z); pk.u[7]=f2bf(v1.w);
  *((uint4*)(WhB + (size_t)i * 8)) = pk.q;
}

__global__ void k_cvt_wcat(const float* __restrict__ Wa, const float* __restrict__ ba,
                           const float* __restrict__ Wb, const float* __restrict__ bb,
                           const float* __restrict__ Wva, const float* __restrict__ bva,
                           const float* __restrict__ Wvb, const float* __restrict__ bvb,
                           u16* __restrict__ Wcat, float* __restrict__ bcat) {
  int r = blockIdx.x;        // 144 rows
  int t = threadIdx.x;
  const float* src = nullptr; float bias = 0.f;
  if      (r < 4)   { src = Wa  + (size_t)r        * KHM; bias = ba[r];      }
  else if (r < 8)   { src = Wb  + (size_t)(r - 4)  * KHM; bias = bb[r - 4];  }
  else if (r < 72)  { src = Wva + (size_t)(r - 8)  * KHM; bias = bva[r - 8]; }
  else if (r < 136) { src = Wvb + (size_t)(r - 72) * KHM; bias = bvb[r - 72];}
  if (t == 0) bcat[r] = bias;
  if (t < 160) {
    int col = t * 8;
    union { u16 u[8]; uint4 q; } pk;
    if (src) {
      float4 v0 = ((const float4*)(src + col))[0];
      float4 v1 = ((const float4*)(src + col))[1];
      pk.u[0]=f2bf(v0.x); pk.u[1]=f2bf(v0.y); pk.u[2]=f2bf(v0.z); pk.u[3]=f2bf(v0.w);
      pk.u[4]=f2bf(v1.x); pk.u[5]=f2bf(v1.y); pk.u[6]=f2bf(v1.z); pk.u[7]=f2bf(v1.w);
    } else {
      pk.q = make_uint4(0, 0, 0, 0);
    }
    *((uint4*)(Wcat + (size_t)r * KHM + col)) = pk.q;
  }
}

// ---- GEMM1: h = relu(Abig @ WhB^T + bh) --------------------------------
// 128x128 tile, BK=64, 4 waves (2x2), m97 structure.
__global__ void k_gemm1(const u16* __restrict__ Abig, const u16* __restrict__ WhB,
                        const float* __restrict__ bh,
                        float* __restrict__ outH, u16* __restrict__ hm) {
  __shared__ u16 As[128 * 64];
  __shared__ u16 Bs[128 * 64];
  const int tid = threadIdx.x;
  const int bid = blockIdx.x;
  // XCD-aware swizzle: 512 blocks, 8 XCDs, 64 blocks/XCD chunk
  const int swz = (bid & 7) * 64 + (bid >> 3);
  const int br = swz >> 3;   // 0..63 row tile
  const int bc = swz & 7;    // 0..7  col tile
  const int wid = tid >> 6, lane = tid & 63;
  const int wr = wid >> 1, wc = wid & 1;
  const int lr = lane & 15, lko = lane >> 4;

  const f32x4 vz = {0.f, 0.f, 0.f, 0.f};
  f32x4 acc[4][4];
#pragma unroll
  for (int m = 0; m < 4; ++m)
#pragma unroll
    for (int n = 0; n < 4; ++n) acc[m][n] = vz;

  const int sRow = tid >> 3;          // 0..31
  const int sCol = (tid & 7) * 8;     // 0..56
  const u16* gA = Abig + (size_t)(br * 128 + sRow) * KIN + sCol;
  const u16* gB = WhB  + (size_t)(bc * 128 + sRow) * KIN + sCol;

  for (int kt = 0; kt < KIN / 64; ++kt) {
    const int kofs = kt * 64;
#pragma unroll
    for (int q = 0; q < 4; ++q) {
      gload16(gA + (size_t)(q * 32) * KIN + kofs, As + q * 2048 + tid * 8);
      gload16(gB + (size_t)(q * 32) * KIN + kofs, Bs + q * 2048 + tid * 8);
    }
    __syncthreads();
#pragma unroll
    for (int kk = 0; kk < 64; kk += 32) {
      bf16x8 a[4], b[4];
#pragma unroll
      for (int m = 0; m < 4; ++m)
        a[m] = *(const bf16x8*)&As[(wr * 64 + m * 16 + lr) * 64 + kk + lko * 8];
#pragma unroll
      for (int n = 0; n < 4; ++n)
        b[n] = *(const bf16x8*)&Bs[(wc * 64 + n * 16 + lr) * 64 + kk + lko * 8];
#pragma unroll
      for (int m = 0; m < 4; ++m)
#pragma unroll
        for (int n = 0; n < 4; ++n)
          acc[m][n] = __builtin_amdgcn_mfma_f32_16x16x32_bf16(a[m], b[n], acc[m][n], 0, 0, 0);
    }
    __syncthreads();
  }

  const int rowBase = br * 128 + wr * 64;
  const int colBase = bc * 128 + wc * 64;
#pragma unroll
  for (int n = 0; n < 4; ++n) {
    const int col = colBase + n * 16 + lr;
    const float bias = bh[col];
#pragma unroll
    for (int m = 0; m < 4; ++m) {
#pragma unroll
      for (int r = 0; r < 4; ++r) {
        const int row = rowBase + m * 16 + lko * 4 + r;
        float v = fmaxf(acc[m][n][r] + bias, 0.0f);
        outH[(size_t)row * HID + col] = v;
        hm[(size_t)row * KHM + col] = f2bf(v);
      }
    }
  }
}

// ---- GEMM2 + tail: u = hm @ Wcat^T + bcat ; memory update --------------
__device__ __forceinline__ float p5(float x) {
  float a = fabsf(x);
  float a2 = a * a;
  return a2 * a2 * a;
}

__global__ void k_gemm2(const u16* __restrict__ hm, const u16* __restrict__ Wcat,
                        const float* __restrict__ bcat,
                        const float* __restrict__ mem, float* __restrict__ outM) {
  __shared__ union {
    struct { u16 As[64 * 64]; u16 Bs[NCAT * 64]; } s;
    float uS[64][148];
  } sm;
  const int tid = threadIdx.x;
  const int bid = blockIdx.x;           // 128 blocks of 64 rows
  const int wid = tid >> 6, lane = tid & 63;
  const int lr = lane & 15, lko = lane >> 4;
  const int rowBase = bid * 64;

  const f32x4 vz = {0.f, 0.f, 0.f, 0.f};
  f32x4 acc[9];
#pragma unroll
  for (int n = 0; n < 9; ++n) acc[n] = vz;

  const int sRow = tid >> 3;
  const int sCol = (tid & 7) * 8;

  for (int kt = 0; kt < KHM / 64; ++kt) {
    const int kofs = kt * 64;
#pragma unroll
    for (int q = 0; q < 2; ++q)
      gload16(hm + (size_t)(rowBase + q * 32 + sRow) * KHM + kofs + sCol,
              sm.s.As + q * 2048 + tid * 8);
#pragma unroll
    for (int q = 0; q < 4; ++q)
      gload16(Wcat + (size_t)(q * 32 + sRow) * KHM + kofs + sCol,
              sm.s.Bs + q * 2048 + tid * 8);
    if (tid < 128)
      gload16(Wcat + (size_t)(128 + sRow) * KHM + kofs + sCol,
              sm.s.Bs + 8192 + tid * 8);
    __syncthreads();
#pragma unroll
    for (int kk = 0; kk < 64; kk += 32) {
      bf16x8 a = *(const bf16x8*)&sm.s.As[(wid * 16 + lr) * 64 + kk + lko * 8];
#pragma unroll
      for (int n = 0; n < 9; ++n) {
        bf16x8 b = *(const bf16x8*)&sm.s.Bs[(n * 16 + lr) * 64 + kk + lko * 8];
        acc[n] = __builtin_amdgcn_mfma_f32_16x16x32_bf16(a, b, acc[n], 0, 0, 0);
      }
    }
    __syncthreads();
  }

  // u tile (with bias) -> LDS
#pragma unroll
  for (int n = 0; n < 9; ++n) {
    const int col = n * 16 + lr;
    const float bias = bcat[col];
#pragma unroll
    for (int r = 0; r < 4; ++r)
      sm.uS[wid * 16 + lko * 4 + r][col] = acc[n][r] + bias;
  }
  __syncthreads();

  // tail: 4 threads per row, each handles 64 of 256 memory cols
  const int r = tid >> 2;
  const int q = tid & 3;
  const float* U = sm.uS[r];

  float S1a = 0.f, S1b = 0.f;
#pragma unroll
  for (int i = 0; i < 32; ++i) { S1a += p5(U[40 + i]); S1b += p5(U[104 + i]); }

  float sa[4], sb[4];
#pragma unroll
  for (int k = 0; k < 4; ++k) {
    float S0a = 0.f, S0b = 0.f;
#pragma unroll
    for (int i = 0; i < 8; ++i) {
      S0a += p5(U[8  + 8 * k + i]);
      S0b += p5(U[72 + 8 * k + i]);
    }
    float na = powf(S0a * S1a, 0.2f);
    float nb = powf(S0b * S1b, 0.2f);
    sa[k] = U[k]     / fmaxf(na, 1e-12f);
    sb[k] = U[4 + k] / fmaxf(nb, 1e-12f);
  }

  float a0h[2], b0h[2];
#pragma unroll
  for (int h2 = 0; h2 < 2; ++h2) {
    const int i0 = q * 2 + h2;
    float a0 = 0.f, b0 = 0.f;
#pragma unroll
    for (int k = 0; k < 4; ++k) {
      a0 += sa[k] * U[8  + 8 * k + i0];
      b0 += sb[k] * U[72 + 8 * k + i0];
    }
    a0h[h2] = a0; b0h[h2] = b0;
  }

  const size_t rowg = (size_t)(rowBase + r);
  const float* memR = mem  + rowg * MEMD + q * 64;
  float*       outR = outM + rowg * MEMD + q * 64;
#pragma unroll
  for (int j = 0; j < 16; ++j) {
    const int hh = j >> 3;
    const int i1 = (j * 4) & 31;
    float4 mv = ((const float4*)memR)[j];
    const float a0 = a0h[hh], b0 = b0h[hh];
    float4 o;
    o.x = mv.x + 0.25f * (a0 * U[40 + i1]     - b0 * U[104 + i1]);
    o.y = mv.y + 0.25f * (a0 * U[40 + i1 + 1] - b0 * U[104 + i1 + 1]);
    o.z = mv.z + 0.25f * (a0 * U[40 + i1 + 2] - b0 * U[104 + i1 + 2]);
    o.w = mv.w + 0.25f * (a0 * U[40 + i1 + 3] - b0 * U[104 + i1 + 3]);
    ((float4*)outR)[j] = o;
  }
}

// ---- launch ------------------------------------------------------------
extern "C" void kernel_launch(void* const* d_in, const int* in_sizes, int n_in,
                              void* d_out, int out_size, void* d_ws, size_t ws_size,
                              hipStream_t stream) {
  const float* x   = (const float*)d_in[0];
  const float* h0  = (const float*)d_in[1];
  const float* mem = (const float*)d_in[2];
  const float* Wh  = (const float*)d_in[3];
  const float* bh  = (const float*)d_in[4];
  const float* Wa  = (const float*)d_in[5];
  const float* ba  = (const float*)d_in[6];
  const float* Wb  = (const float*)d_in[7];
  const float* bb  = (const float*)d_in[8];
  const float* Wva = (const float*)d_in[9];
  const float* bva = (const float*)d_in[10];
  const float* Wvb = (const float*)d_in[11];
  const float* bvb = (const float*)d_in[12];

  float* outM = (float*)d_out;                          // 8192*256
  float* outH = (float*)d_out + (size_t)B_ROWS * MEMD;  // 8192*1024

  char* ws = (char*)d_ws;
  u16*   Abig = (u16*)(ws);                  // 8192*2304*2 = 37,748,736
  u16*   WhB  = (u16*)(ws + 37748736);       // 1024*2304*2 =  4,718,592
  u16*   hmB  = (u16*)(ws + 42467328);       // 8192*1280*2 = 20,971,520
  u16*   Wcat = (u16*)(ws + 63438848);       // 144*1280*2  =    368,640
  float* bcat = (float*)(ws + 63807488);     // 144*4

  k_cvt_xh  <<<dim3(2048), dim3(256), 0, stream>>>(x, h0, Abig);
  k_cvt_mem <<<dim3(1024), dim3(256), 0, stream>>>(mem, Abig, hmB);
  k_cvt_wh  <<<dim3(1152), dim3(256), 0, stream>>>(Wh, WhB);
  k_cvt_wcat<<<dim3(144),  dim3(256), 0, stream>>>(Wa, ba, Wb, bb, Wva, bva, Wvb, bvb, Wcat, bcat);
  k_gemm1   <<<dim3(512),  dim3(256), 0, stream>>>(Abig, WhB, bh, outH, hmB);
  k_gemm2   <<<dim3(128),  dim3(256), 0, stream>>>(hmB, Wcat, bcat, mem, outM);
}

// Round 2
// 239.248 us; speedup vs baseline: 1.3376x; 1.3376x over previous
//
#include <hip/hip_runtime.h>
#include <stdint.h>

#define B_ROWS 8192
#define INP    1024
#define HID    1024
#define MEMD   256
#define KIN    2304   // INP+HID+MEMD
#define KHM    1280   // HID+MEMD
#define NCAT   144    // 136 outputs padded to 144

typedef unsigned short u16;
typedef unsigned int   u32;
typedef __attribute__((ext_vector_type(8))) short bf16x8;
typedef __attribute__((ext_vector_type(4))) float f32x4;

__device__ __forceinline__ u16 f2bf(float f) {
  u32 b = __builtin_bit_cast(u32, f);
  u32 r = b + 0x7FFF + ((b >> 16) & 1);   // RNE
  return (u16)(r >> 16);
}

__device__ __forceinline__ void gload16(const void* g, void* l) {
  __builtin_amdgcn_global_load_lds(
      (const __attribute__((address_space(1))) u32*)g,
      (__attribute__((address_space(3))) u32*)l, 16, 0, 0);
}

// ---- converters --------------------------------------------------------
__global__ void k_cvt_xh(const float* __restrict__ x, const float* __restrict__ h0,
                         u16* __restrict__ Abig) {
  const int nIter = B_ROWS * 2048 / 8;  // 2,097,152 groups of 8
  for (int i = blockIdx.x * blockDim.x + threadIdx.x; i < nIter;
       i += gridDim.x * blockDim.x) {
    int row = i >> 8;             // 256 groups per row
    int col = (i & 255) * 8;
    const float* src = (col < 1024) ? (x + (size_t)row * 1024 + col)
                                    : (h0 + (size_t)row * 1024 + (col - 1024));
    float4 v0 = ((const float4*)src)[0];
    float4 v1 = ((const float4*)src)[1];
    union { u16 u[8]; uint4 q; } pk;
    pk.u[0]=f2bf(v0.x); pk.u[1]=f2bf(v0.y); pk.u[2]=f2bf(v0.z); pk.u[3]=f2bf(v0.w);
    pk.u[4]=f2bf(v1.x); pk.u[5]=f2bf(v1.y); pk.u[6]=f2bf(v1.z); pk.u[7]=f2bf(v1.w);
    *((uint4*)(Abig + (size_t)row * KIN + col)) = pk.q;
  }
}

__global__ void k_cvt_mem(const float* __restrict__ mem,
                          u16* __restrict__ Abig, u16* __restrict__ hm) {
  int i = blockIdx.x * blockDim.x + threadIdx.x;  // 262,144 threads exactly
  int row = i >> 5;
  int col = (i & 31) * 8;
  const float* src = mem + (size_t)row * MEMD + col;
  float4 v0 = ((const float4*)src)[0];
  float4 v1 = ((const float4*)src)[1];
  union { u16 u[8]; uint4 q; } pk;
  pk.u[0]=f2bf(v0.x); pk.u[1]=f2bf(v0.y); pk.u[2]=f2bf(v0.z); pk.u[3]=f2bf(v0.w);
  pk.u[4]=f2bf(v1.x); pk.u[5]=f2bf(v1.y); pk.u[6]=f2bf(v1.z); pk.u[7]=f2bf(v1.w);
  *((uint4*)(Abig + (size_t)row * KIN + 2048 + col)) = pk.q;
  *((uint4*)(hm   + (size_t)row * KHM + 1024 + col)) = pk.q;
}

__global__ void k_cvt_wh(const float* __restrict__ Wh, u16* __restrict__ WhB) {
  int i = blockIdx.x * blockDim.x + threadIdx.x;  // 294,912 threads exactly
  const float* src = Wh + (size_t)i * 8;
  float4 v0 = ((const float4*)src)[0];
  float4 v1 = ((const float4*)src)[1];
  union { u16 u[8]; uint4 q; } pk;
  pk.u[0]=f2bf(v0.x); pk.u[1]=f2bf(v0.y); pk.u[2]=f2bf(v0.z); pk.u[3]=f2bf(v0.w);
  pk.u[4]=f2bf(v1.x); pk.u[5]=f2bf(v1.y); pk.u[6]=f2bf(v1.z); pk.u[7]=f2bf(v1.w);
  *((uint4*)(WhB + (size_t)i * 8)) = pk.q;
}

__global__ void k_cvt_wcat(const float* __restrict__ Wa, const float* __restrict__ ba,
                           const float* __restrict__ Wb, const float* __restrict__ bb,
                           const float* __restrict__ Wva, const float* __restrict__ bva,
                           const float* __restrict__ Wvb, const float* __restrict__ bvb,
                           u16* __restrict__ Wcat, float* __restrict__ bcat) {
  int r = blockIdx.x;        // 144 rows
  int t = threadIdx.x;
  const float* src = nullptr; float bias = 0.f;
  if      (r < 4)   { src = Wa  + (size_t)r        * KHM; bias = ba[r];      }
  else if (r < 8)   { src = Wb  + (size_t)(r - 4)  * KHM; bias = bb[r - 4];  }
  else if (r < 72)  { src = Wva + (size_t)(r - 8)  * KHM; bias = bva[r - 8]; }
  else if (r < 136) { src = Wvb + (size_t)(r - 72) * KHM; bias = bvb[r - 72];}
  if (t == 0) bcat[r] = bias;
  if (t < 160) {
    int col = t * 8;
    union { u16 u[8]; uint4 q; } pk;
    if (src) {
      float4 v0 = ((const float4*)(src + col))[0];
      float4 v1 = ((const float4*)(src + col))[1];
      pk.u[0]=f2bf(v0.x); pk.u[1]=f2bf(v0.y); pk.u[2]=f2bf(v0.z); pk.u[3]=f2bf(v0.w);
      pk.u[4]=f2bf(v1.x); pk.u[5]=f2bf(v1.y); pk.u[6]=f2bf(v1.z); pk.u[7]=f2bf(v1.w);
    } else {
      pk.q = make_uint4(0, 0, 0, 0);
    }
    *((uint4*)(Wcat + (size_t)r * KHM + col)) = pk.q;
  }
}

// ---- GEMM1: h = relu(Abig @ WhB^T + bh) --------------------------------
// 128x128 tile, BK=64, 4 waves (2x2), m97 structure.
__global__ void k_gemm1(const u16* __restrict__ Abig, const u16* __restrict__ WhB,
                        const float* __restrict__ bh,
                        float* __restrict__ outH, u16* __restrict__ hm) {
  __shared__ u16 As[128 * 64];
  __shared__ u16 Bs[128 * 64];
  const int tid = threadIdx.x;
  const int bid = blockIdx.x;
  // XCD-aware swizzle: 512 blocks, 8 XCDs, 64 blocks/XCD chunk
  const int swz = (bid & 7) * 64 + (bid >> 3);
  const int br = swz >> 3;   // 0..63 row tile
  const int bc = swz & 7;    // 0..7  col tile
  const int wid = tid >> 6, lane = tid & 63;
  const int wr = wid >> 1, wc = wid & 1;
  const int lr = lane & 15, lko = lane >> 4;

  const f32x4 vz = {0.f, 0.f, 0.f, 0.f};
  f32x4 acc[4][4];
#pragma unroll
  for (int m = 0; m < 4; ++m)
#pragma unroll
    for (int n = 0; n < 4; ++n) acc[m][n] = vz;

  const int sRow = tid >> 3;          // 0..31
  const int sCol = (tid & 7) * 8;     // 0..56
  const u16* gA = Abig + (size_t)(br * 128 + sRow) * KIN + sCol;
  const u16* gB = WhB  + (size_t)(bc * 128 + sRow) * KIN + sCol;

  for (int kt = 0; kt < KIN / 64; ++kt) {
    const int kofs = kt * 64;
#pragma unroll
    for (int q = 0; q < 4; ++q) {
      gload16(gA + (size_t)(q * 32) * KIN + kofs, As + q * 2048 + tid * 8);
      gload16(gB + (size_t)(q * 32) * KIN + kofs, Bs + q * 2048 + tid * 8);
    }
    __syncthreads();
#pragma unroll
    for (int kk = 0; kk < 64; kk += 32) {
      bf16x8 a[4], b[4];
#pragma unroll
      for (int m = 0; m < 4; ++m)
        a[m] = *(const bf16x8*)&As[(wr * 64 + m * 16 + lr) * 64 + kk + lko * 8];
#pragma unroll
      for (int n = 0; n < 4; ++n)
        b[n] = *(const bf16x8*)&Bs[(wc * 64 + n * 16 + lr) * 64 + kk + lko * 8];
#pragma unroll
      for (int m = 0; m < 4; ++m)
#pragma unroll
        for (int n = 0; n < 4; ++n)
          acc[m][n] = __builtin_amdgcn_mfma_f32_16x16x32_bf16(a[m], b[n], acc[m][n], 0, 0, 0);
    }
    __syncthreads();
  }

  const int rowBase = br * 128 + wr * 64;
  const int colBase = bc * 128 + wc * 64;
#pragma unroll
  for (int n = 0; n < 4; ++n) {
    const int col = colBase + n * 16 + lr;
    const float bias = bh[col];
#pragma unroll
    for (int m = 0; m < 4; ++m) {
#pragma unroll
      for (int r = 0; r < 4; ++r) {
        const int row = rowBase + m * 16 + lko * 4 + r;
        float v = fmaxf(acc[m][n][r] + bias, 0.0f);
        outH[(size_t)row * HID + col] = v;
        hm[(size_t)row * KHM + col] = f2bf(v);
      }
    }
  }
}

// ---- GEMM2 + tail: u = hm @ Wcat^T + bcat ; memory update --------------
// Split-K across 4 waves, 16 rows/block, 512 blocks. No LDS staging for the
// GEMM (fragments straight from L2; zero reuse would be gained by staging),
// no barriers in main loop. LDS only for the cross-wave partial reduction
// and the u tile consumed by the tail.
__device__ __forceinline__ float p5(float x) {
  float a = fabsf(x);
  float a2 = a * a;
  return a2 * a2 * a;
}

__global__ void __launch_bounds__(256, 2)
k_gemm2(const u16* __restrict__ hm, const u16* __restrict__ Wcat,
        const float* __restrict__ bcat,
        const float* __restrict__ mem, float* __restrict__ outM) {
  // stride 148 floats: 592 B row pitch, 16B-aligned for float4 LDS reads
  __shared__ float pS[4][16][148];
  const int tid = threadIdx.x;
  const int bid = blockIdx.x;           // 512 blocks of 16 rows
  const int wid = tid >> 6, lane = tid & 63;
  const int lr = lane & 15, lko = lane >> 4;
  const int rowBase = bid * 16;

  const f32x4 vz = {0.f, 0.f, 0.f, 0.f};
  f32x4 acc[9];
#pragma unroll
  for (int n = 0; n < 9; ++n) acc[n] = vz;

  // fragment base pointers (A row = lr, B row = n*16+lr, k = lko*8 + ...)
  const u16* gA = hm   + (size_t)(rowBase + lr) * KHM + lko * 8;
  const u16* gB = Wcat + (size_t)lr * KHM + lko * 8;

  // wave w handles k64-chunks {c*4 + w : c=0..4}  (interleaved for L2 locality)
  for (int c = 0; c < 5; ++c) {
    const int kofs = (c * 4 + wid) * 64;
#pragma unroll
    for (int h = 0; h < 2; ++h) {
      const int ko = kofs + h * 32;
      bf16x8 a = *(const bf16x8*)(gA + ko);
      bf16x8 b[9];
#pragma unroll
      for (int n = 0; n < 9; ++n)
        b[n] = *(const bf16x8*)(gB + (size_t)(n * 16) * KHM + ko);
#pragma unroll
      for (int n = 0; n < 9; ++n)
        acc[n] = __builtin_amdgcn_mfma_f32_16x16x32_bf16(a, b[n], acc[n], 0, 0, 0);
    }
  }

  // write per-wave partials (row = lko*4+r, col = n*16+lr)
#pragma unroll
  for (int n = 0; n < 9; ++n)
#pragma unroll
    for (int r = 0; r < 4; ++r)
      pS[wid][lko * 4 + r][n * 16 + lr] = acc[n][r];
  __syncthreads();

  // reduce 4 partials + bias -> pS[0]
  {
    const int rr = tid >> 4;            // 0..15
    const int cb = (tid & 15) * 9;      // 0..135
#pragma unroll
    for (int i = 0; i < 9; ++i) {
      const int col = cb + i;
      float s = pS[0][rr][col] + pS[1][rr][col] + pS[2][rr][col] + pS[3][rr][col]
              + bcat[col];
      pS[0][rr][col] = s;
    }
  }
  __syncthreads();

  // tail: 16 threads per row
  const int r = tid >> 4;
  const int t = tid & 15;
  const float* U = &pS[0][r][0];

  float S1a = 0.f, S1b = 0.f;
  {
    const float4* Ua = (const float4*)(U + 40);
    const float4* Ub = (const float4*)(U + 104);
#pragma unroll
    for (int i = 0; i < 8; ++i) {
      float4 va = Ua[i], vb = Ub[i];
      S1a += p5(va.x) + p5(va.y) + p5(va.z) + p5(va.w);
      S1b += p5(vb.x) + p5(vb.y) + p5(vb.z) + p5(vb.w);
    }
  }

  float sa[4], sb[4];
#pragma unroll
  for (int k = 0; k < 4; ++k) {
    const float4* Pa = (const float4*)(U + 8 + 8 * k);
    const float4* Pb = (const float4*)(U + 72 + 8 * k);
    float4 a0v = Pa[0], a1v = Pa[1], b0v = Pb[0], b1v = Pb[1];
    float S0a = p5(a0v.x) + p5(a0v.y) + p5(a0v.z) + p5(a0v.w)
              + p5(a1v.x) + p5(a1v.y) + p5(a1v.z) + p5(a1v.w);
    float S0b = p5(b0v.x) + p5(b0v.y) + p5(b0v.z) + p5(b0v.w)
              + p5(b1v.x) + p5(b1v.y) + p5(b1v.z) + p5(b1v.w);
    float na = exp2f(0.2f * log2f(S0a * S1a));   // (S0*S1)^(1/5)
    float nb = exp2f(0.2f * log2f(S0b * S1b));
    sa[k] = 0.25f * U[k]     / fmaxf(na, 1e-12f);
    sb[k] = 0.25f * U[4 + k] / fmaxf(nb, 1e-12f);
  }

  // this thread covers memory cols [t*16, t*16+16) -> j0 = t>>1 fixed
  const int j0 = t >> 1;
  float A0 = 0.f, B0 = 0.f;
#pragma unroll
  for (int k = 0; k < 4; ++k) {
    A0 += sa[k] * U[8  + 8 * k + j0];
    B0 += sb[k] * U[72 + 8 * k + j0];
  }

  const int i1b = (t & 1) * 16;
  const size_t rowg = (size_t)(rowBase + r);
  const float4* memR = (const float4*)(mem  + rowg * MEMD + t * 16);
  float4*       outR = (float4*)      (outM + rowg * MEMD + t * 16);
#pragma unroll
  for (int j = 0; j < 4; ++j) {
    float4 mv = memR[j];
    float4 ua = *(const float4*)(U + 40  + i1b + j * 4);
    float4 ub = *(const float4*)(U + 104 + i1b + j * 4);
    float4 o;
    o.x = mv.x + A0 * ua.x - B0 * ub.x;
    o.y = mv.y + A0 * ua.y - B0 * ub.y;
    o.z = mv.z + A0 * ua.z - B0 * ub.z;
    o.w = mv.w + A0 * ua.w - B0 * ub.w;
    outR[j] = o;
  }
}

// ---- launch ------------------------------------------------------------
extern "C" void kernel_launch(void* const* d_in, const int* in_sizes, int n_in,
                              void* d_out, int out_size, void* d_ws, size_t ws_size,
                              hipStream_t stream) {
  const float* x   = (const float*)d_in[0];
  const float* h0  = (const float*)d_in[1];
  const float* mem = (const float*)d_in[2];
  const float* Wh  = (const float*)d_in[3];
  const float* bh  = (const float*)d_in[4];
  const float* Wa  = (const float*)d_in[5];
  const float* ba  = (const float*)d_in[6];
  const float* Wb  = (const float*)d_in[7];
  const float* bb  = (const float*)d_in[8];
  const float* Wva = (const float*)d_in[9];
  const float* bva = (const float*)d_in[10];
  const float* Wvb = (const float*)d_in[11];
  const float* bvb = (const float*)d_in[12];

  float* outM = (float*)d_out;                          // 8192*256
  float* outH = (float*)d_out + (size_t)B_ROWS * MEMD;  // 8192*1024

  char* ws = (char*)d_ws;
  u16*   Abig = (u16*)(ws);                  // 8192*2304*2 = 37,748,736
  u16*   WhB  = (u16*)(ws + 37748736);       // 1024*2304*2 =  4,718,592
  u16*   hmB  = (u16*)(ws + 42467328);       // 8192*1280*2 = 20,971,520
  u16*   Wcat = (u16*)(ws + 63438848);       // 144*1280*2  =    368,640
  float* bcat = (float*)(ws + 63807488);     // 144*4

  k_cvt_xh  <<<dim3(2048), dim3(256), 0, stream>>>(x, h0, Abig);
  k_cvt_mem <<<dim3(1024), dim3(256), 0, stream>>>(mem, Abig, hmB);
  k_cvt_wh  <<<dim3(1152), dim3(256), 0, stream>>>(Wh, WhB);
  k_cvt_wcat<<<dim3(144),  dim3(256), 0, stream>>>(Wa, ba, Wb, bb, Wva, bva, Wvb, bvb, Wcat, bcat);
  k_gemm1   <<<dim3(512),  dim3(256), 0, stream>>>(Abig, WhB, bh, outH, hmB);
  k_gemm2   <<<dim3(512),  dim3(256), 0, stream>>>(hmB, Wcat, bcat, mem, outM);
}

// Round 3
// 226.354 us; speedup vs baseline: 1.4138x; 1.0570x over previous
//
#include <hip/hip_runtime.h>
#include <stdint.h>

#define B_ROWS 8192
#define INP    1024
#define HID    1024
#define MEMD   256
#define KIN    2304   // INP+HID+MEMD
#define KHM    1280   // HID+MEMD
#define NCAT   144    // 136 outputs padded to 144

typedef unsigned short u16;
typedef unsigned int   u32;
typedef __attribute__((ext_vector_type(8))) short bf16x8;
typedef __attribute__((ext_vector_type(4))) float f32x4;

__device__ __forceinline__ u16 f2bf(float f) {
  u32 b = __builtin_bit_cast(u32, f);
  u32 r = b + 0x7FFF + ((b >> 16) & 1);   // RNE
  return (u16)(r >> 16);
}

__device__ __forceinline__ void gload16(const void* g, void* l) {
  __builtin_amdgcn_global_load_lds(
      (const __attribute__((address_space(1))) u32*)g,
      (__attribute__((address_space(3))) u32*)l, 16, 0, 0);
}

// ---- converters --------------------------------------------------------
__global__ void k_cvt_xh(const float* __restrict__ x, const float* __restrict__ h0,
                         u16* __restrict__ Abig) {
  const int nIter = B_ROWS * 2048 / 8;  // 2,097,152 groups of 8
  for (int i = blockIdx.x * blockDim.x + threadIdx.x; i < nIter;
       i += gridDim.x * blockDim.x) {
    int row = i >> 8;             // 256 groups per row
    int col = (i & 255) * 8;
    const float* src = (col < 1024) ? (x + (size_t)row * 1024 + col)
                                    : (h0 + (size_t)row * 1024 + (col - 1024));
    float4 v0 = ((const float4*)src)[0];
    float4 v1 = ((const float4*)src)[1];
    union { u16 u[8]; uint4 q; } pk;
    pk.u[0]=f2bf(v0.x); pk.u[1]=f2bf(v0.y); pk.u[2]=f2bf(v0.z); pk.u[3]=f2bf(v0.w);
    pk.u[4]=f2bf(v1.x); pk.u[5]=f2bf(v1.y); pk.u[6]=f2bf(v1.z); pk.u[7]=f2bf(v1.w);
    *((uint4*)(Abig + (size_t)row * KIN + col)) = pk.q;
  }
}

__global__ void k_cvt_mem(const float* __restrict__ mem,
                          u16* __restrict__ Abig, u16* __restrict__ hm) {
  int i = blockIdx.x * blockDim.x + threadIdx.x;  // 262,144 threads exactly
  int row = i >> 5;
  int col = (i & 31) * 8;
  const float* src = mem + (size_t)row * MEMD + col;
  float4 v0 = ((const float4*)src)[0];
  float4 v1 = ((const float4*)src)[1];
  union { u16 u[8]; uint4 q; } pk;
  pk.u[0]=f2bf(v0.x); pk.u[1]=f2bf(v0.y); pk.u[2]=f2bf(v0.z); pk.u[3]=f2bf(v0.w);
  pk.u[4]=f2bf(v1.x); pk.u[5]=f2bf(v1.y); pk.u[6]=f2bf(v1.z); pk.u[7]=f2bf(v1.w);
  *((uint4*)(Abig + (size_t)row * KIN + 2048 + col)) = pk.q;
  *((uint4*)(hm   + (size_t)row * KHM + 1024 + col)) = pk.q;
}

__global__ void k_cvt_wh(const float* __restrict__ Wh, u16* __restrict__ WhB) {
  int i = blockIdx.x * blockDim.x + threadIdx.x;  // 294,912 threads exactly
  const float* src = Wh + (size_t)i * 8;
  float4 v0 = ((const float4*)src)[0];
  float4 v1 = ((const float4*)src)[1];
  union { u16 u[8]; uint4 q; } pk;
  pk.u[0]=f2bf(v0.x); pk.u[1]=f2bf(v0.y); pk.u[2]=f2bf(v0.z); pk.u[3]=f2bf(v0.w);
  pk.u[4]=f2bf(v1.x); pk.u[5]=f2bf(v1.y); pk.u[6]=f2bf(v1.z); pk.u[7]=f2bf(v1.w);
  *((uint4*)(WhB + (size_t)i * 8)) = pk.q;
}

__global__ void k_cvt_wcat(const float* __restrict__ Wa, const float* __restrict__ ba,
                           const float* __restrict__ Wb, const float* __restrict__ bb,
                           const float* __restrict__ Wva, const float* __restrict__ bva,
                           const float* __restrict__ Wvb, const float* __restrict__ bvb,
                           u16* __restrict__ Wcat, float* __restrict__ bcat) {
  int r = blockIdx.x;        // 144 rows
  int t = threadIdx.x;
  const float* src = nullptr; float bias = 0.f;
  if      (r < 4)   { src = Wa  + (size_t)r        * KHM; bias = ba[r];      }
  else if (r < 8)   { src = Wb  + (size_t)(r - 4)  * KHM; bias = bb[r - 4];  }
  else if (r < 72)  { src = Wva + (size_t)(r - 8)  * KHM; bias = bva[r - 8]; }
  else if (r < 136) { src = Wvb + (size_t)(r - 72) * KHM; bias = bvb[r - 72];}
  if (t == 0) bcat[r] = bias;
  if (t < 160) {
    int col = t * 8;
    union { u16 u[8]; uint4 q; } pk;
    if (src) {
      float4 v0 = ((const float4*)(src + col))[0];
      float4 v1 = ((const float4*)(src + col))[1];
      pk.u[0]=f2bf(v0.x); pk.u[1]=f2bf(v0.y); pk.u[2]=f2bf(v0.z); pk.u[3]=f2bf(v0.w);
      pk.u[4]=f2bf(v1.x); pk.u[5]=f2bf(v1.y); pk.u[6]=f2bf(v1.z); pk.u[7]=f2bf(v1.w);
    } else {
      pk.q = make_uint4(0, 0, 0, 0);
    }
    *((uint4*)(Wcat + (size_t)r * KHM + col)) = pk.q;
  }
}

// ---- GEMM1: h = relu(Abig @ WhB^T + bh) --------------------------------
// 128x128 tile, BK=64, 4 waves (2x2). Round-3 structure:
//   - double-buffered LDS (2x32 KB), raw s_barrier, counted vmcnt(8)
//     (prefetch loads stay in flight across the barrier -> no drain stall)
//   - T2 XOR swizzle slot^=(row&7): linear gload_lds dest, inverse-swizzled
//     global source, swizzled ds_read (rule #21 both-sides involution)
//   - s_setprio(1) around MFMA clusters, sched_barrier(0) pins
__global__ void __launch_bounds__(256, 2)
k_gemm1(const u16* __restrict__ Abig, const u16* __restrict__ WhB,
        const float* __restrict__ bh,
        float* __restrict__ outH, u16* __restrict__ hm) {
  __shared__ u16 As[2][128 * 64];
  __shared__ u16 Bs[2][128 * 64];
  const int tid = threadIdx.x;
  const int bid = blockIdx.x;
  // XCD-aware swizzle: 512 blocks, 8 XCDs, 64 blocks/XCD (8 br x 8 bc each)
  const int swz = (bid & 7) * 64 + (bid >> 3);
  const int br = swz >> 3;   // 0..63 row tile
  const int bc = swz & 7;    // 0..7  col tile
  const int wid = tid >> 6, lane = tid & 63;
  const int wr = wid >> 1, wc = wid & 1;
  const int lr = lane & 15, lko = lane >> 4;

  const f32x4 vz = {0.f, 0.f, 0.f, 0.f};
  f32x4 acc[4][4];
#pragma unroll
  for (int m = 0; m < 4; ++m)
#pragma unroll
    for (int n = 0; n < 4; ++n) acc[m][n] = vz;

  // staging: chunk c = q*256+tid -> LDS row c>>3, dest slot c&7 (linear).
  // source slot = dest ^ (row&7); q*32 doesn't change row&7 -> q-invariant.
  const int sRow   = tid >> 3;                       // 0..31
  const int sSlotG = (tid & 7) ^ (sRow & 7);         // swizzled source slot
  const u16* gA = Abig + (size_t)(br * 128 + sRow) * KIN + sSlotG * 8;
  const u16* gB = WhB  + (size_t)(bc * 128 + sRow) * KIN + sSlotG * 8;

  // fragment read bases (swizzled slots)
  const int sx  = lr & 7;
  const int s0  = ((0 + lko) ^ sx) * 8;   // kk=0  slot
  const int s1  = ((4 + lko) ^ sx) * 8;   // kk=32 slot
  const int axr = (wr * 64 + lr) * 64;    // + m*1024
  const int bxr = (wc * 64 + lr) * 64;    // + n*1024

  // prologue: stage tile 0 into buf 0
#pragma unroll
  for (int q = 0; q < 4; ++q) {
    gload16(gA + (size_t)(q * 32) * KIN, &As[0][q * 2048 + tid * 8]);
    gload16(gB + (size_t)(q * 32) * KIN, &Bs[0][q * 2048 + tid * 8]);
  }

  for (int kt = 0; kt < KIN / 64; ++kt) {
    const int cur = kt & 1;
    if (kt < KIN / 64 - 1) {
      const int kofs = (kt + 1) * 64;
#pragma unroll
      for (int q = 0; q < 4; ++q) {
        gload16(gA + (size_t)(q * 32) * KIN + kofs, &As[1 - cur][q * 2048 + tid * 8]);
        gload16(gB + (size_t)(q * 32) * KIN + kofs, &Bs[1 - cur][q * 2048 + tid * 8]);
      }
      asm volatile("s_waitcnt vmcnt(8)" ::: "memory");  // tile-kt loads done
    } else {
      asm volatile("s_waitcnt vmcnt(0)" ::: "memory");
    }
    __builtin_amdgcn_s_barrier();
    __builtin_amdgcn_sched_barrier(0);

    const u16* Ac = &As[cur][0];
    const u16* Bc = &Bs[cur][0];
    {
      bf16x8 a[4], b[4];
#pragma unroll
      for (int m = 0; m < 4; ++m) a[m] = *(const bf16x8*)&Ac[axr + m * 1024 + s0];
#pragma unroll
      for (int n = 0; n < 4; ++n) b[n] = *(const bf16x8*)&Bc[bxr + n * 1024 + s0];
      __builtin_amdgcn_s_setprio(1);
#pragma unroll
      for (int m = 0; m < 4; ++m)
#pragma unroll
        for (int n = 0; n < 4; ++n)
          acc[m][n] = __builtin_amdgcn_mfma_f32_16x16x32_bf16(a[m], b[n], acc[m][n], 0, 0, 0);
      __builtin_amdgcn_s_setprio(0);
    }
    {
      bf16x8 a[4], b[4];
#pragma unroll
      for (int m = 0; m < 4; ++m) a[m] = *(const bf16x8*)&Ac[axr + m * 1024 + s1];
#pragma unroll
      for (int n = 0; n < 4; ++n) b[n] = *(const bf16x8*)&Bc[bxr + n * 1024 + s1];
      __builtin_amdgcn_s_setprio(1);
#pragma unroll
      for (int m = 0; m < 4; ++m)
#pragma unroll
        for (int n = 0; n < 4; ++n)
          acc[m][n] = __builtin_amdgcn_mfma_f32_16x16x32_bf16(a[m], b[n], acc[m][n], 0, 0, 0);
      __builtin_amdgcn_s_setprio(0);
    }
    __builtin_amdgcn_sched_barrier(0);
    __builtin_amdgcn_s_barrier();   // protect buf[cur] before next-iter STAGE
  }

  const int rowBase = br * 128 + wr * 64;
  const int colBase = bc * 128 + wc * 64;
#pragma unroll
  for (int n = 0; n < 4; ++n) {
    const int col = colBase + n * 16 + lr;
    const float bias = bh[col];
#pragma unroll
    for (int m = 0; m < 4; ++m) {
#pragma unroll
      for (int r = 0; r < 4; ++r) {
        const int row = rowBase + m * 16 + lko * 4 + r;
        float v = fmaxf(acc[m][n][r] + bias, 0.0f);
        outH[(size_t)row * HID + col] = v;
        hm[(size_t)row * KHM + col] = f2bf(v);
      }
    }
  }
}

// ---- GEMM2 + tail: u = hm @ Wcat^T + bcat ; memory update --------------
__device__ __forceinline__ float p5(float x) {
  float a = fabsf(x);
  float a2 = a * a;
  return a2 * a2 * a;
}

__global__ void __launch_bounds__(256, 2)
k_gemm2(const u16* __restrict__ hm, const u16* __restrict__ Wcat,
        const float* __restrict__ bcat,
        const float* __restrict__ mem, float* __restrict__ outM) {
  // stride 148 floats: 592 B row pitch, 16B-aligned for float4 LDS reads
  __shared__ float pS[4][16][148];
  const int tid = threadIdx.x;
  const int bid = blockIdx.x;           // 512 blocks of 16 rows
  const int wid = tid >> 6, lane = tid & 63;
  const int lr = lane & 15, lko = lane >> 4;
  const int rowBase = bid * 16;

  const f32x4 vz = {0.f, 0.f, 0.f, 0.f};
  f32x4 acc[9];
#pragma unroll
  for (int n = 0; n < 9; ++n) acc[n] = vz;

  // fragment base pointers (A row = lr, B row = n*16+lr, k = lko*8 + ...)
  const u16* gA = hm   + (size_t)(rowBase + lr) * KHM + lko * 8;
  const u16* gB = Wcat + (size_t)lr * KHM + lko * 8;

  // wave w handles k64-chunks {c*4 + w : c=0..4}  (interleaved for L2 locality)
  for (int c = 0; c < 5; ++c) {
    const int kofs = (c * 4 + wid) * 64;
#pragma unroll
    for (int h = 0; h < 2; ++h) {
      const int ko = kofs + h * 32;
      bf16x8 a = *(const bf16x8*)(gA + ko);
      bf16x8 b[9];
#pragma unroll
      for (int n = 0; n < 9; ++n)
        b[n] = *(const bf16x8*)(gB + (size_t)(n * 16) * KHM + ko);
#pragma unroll
      for (int n = 0; n < 9; ++n)
        acc[n] = __builtin_amdgcn_mfma_f32_16x16x32_bf16(a, b[n], acc[n], 0, 0, 0);
    }
  }

  // write per-wave partials (row = lko*4+r, col = n*16+lr)
#pragma unroll
  for (int n = 0; n < 9; ++n)
#pragma unroll
    for (int r = 0; r < 4; ++r)
      pS[wid][lko * 4 + r][n * 16 + lr] = acc[n][r];
  __syncthreads();

  // reduce 4 partials + bias -> pS[0]
  {
    const int rr = tid >> 4;            // 0..15
    const int cb = (tid & 15) * 9;      // 0..135
#pragma unroll
    for (int i = 0; i < 9; ++i) {
      const int col = cb + i;
      float s = pS[0][rr][col] + pS[1][rr][col] + pS[2][rr][col] + pS[3][rr][col]
              + bcat[col];
      pS[0][rr][col] = s;
    }
  }
  __syncthreads();

  // tail: 16 threads per row
  const int r = tid >> 4;
  const int t = tid & 15;
  const float* U = &pS[0][r][0];

  float S1a = 0.f, S1b = 0.f;
  {
    const float4* Ua = (const float4*)(U + 40);
    const float4* Ub = (const float4*)(U + 104);
#pragma unroll
    for (int i = 0; i < 8; ++i) {
      float4 va = Ua[i], vb = Ub[i];
      S1a += p5(va.x) + p5(va.y) + p5(va.z) + p5(va.w);
      S1b += p5(vb.x) + p5(vb.y) + p5(vb.z) + p5(vb.w);
    }
  }

  float sa[4], sb[4];
#pragma unroll
  for (int k = 0; k < 4; ++k) {
    const float4* Pa = (const float4*)(U + 8 + 8 * k);
    const float4* Pb = (const float4*)(U + 72 + 8 * k);
    float4 a0v = Pa[0], a1v = Pa[1], b0v = Pb[0], b1v = Pb[1];
    float S0a = p5(a0v.x) + p5(a0v.y) + p5(a0v.z) + p5(a0v.w)
              + p5(a1v.x) + p5(a1v.y) + p5(a1v.z) + p5(a1v.w);
    float S0b = p5(b0v.x) + p5(b0v.y) + p5(b0v.z) + p5(b0v.w)
              + p5(b1v.x) + p5(b1v.y) + p5(b1v.z) + p5(b1v.w);
    float na = exp2f(0.2f * log2f(S0a * S1a));   // (S0*S1)^(1/5)
    float nb = exp2f(0.2f * log2f(S0b * S1b));
    sa[k] = 0.25f * U[k]     / fmaxf(na, 1e-12f);
    sb[k] = 0.25f * U[4 + k] / fmaxf(nb, 1e-12f);
  }

  // this thread covers memory cols [t*16, t*16+16) -> j0 = t>>1 fixed
  const int j0 = t >> 1;
  float A0 = 0.f, B0 = 0.f;
#pragma unroll
  for (int k = 0; k < 4; ++k) {
    A0 += sa[k] * U[8  + 8 * k + j0];
    B0 += sb[k] * U[72 + 8 * k + j0];
  }

  const int i1b = (t & 1) * 16;
  const size_t rowg = (size_t)(rowBase + r);
  const float4* memR = (const float4*)(mem  + rowg * MEMD + t * 16);
  float4*       outR = (float4*)      (outM + rowg * MEMD + t * 16);
#pragma unroll
  for (int j = 0; j < 4; ++j) {
    float4 mv = memR[j];
    float4 ua = *(const float4*)(U + 40  + i1b + j * 4);
    float4 ub = *(const float4*)(U + 104 + i1b + j * 4);
    float4 o;
    o.x = mv.x + A0 * ua.x - B0 * ub.x;
    o.y = mv.y + A0 * ua.y - B0 * ub.y;
    o.z = mv.z + A0 * ua.z - B0 * ub.z;
    o.w = mv.w + A0 * ua.w - B0 * ub.w;
    outR[j] = o;
  }
}

// ---- launch ------------------------------------------------------------
extern "C" void kernel_launch(void* const* d_in, const int* in_sizes, int n_in,
                              void* d_out, int out_size, void* d_ws, size_t ws_size,
                              hipStream_t stream) {
  const float* x   = (const float*)d_in[0];
  const float* h0  = (const float*)d_in[1];
  const float* mem = (const float*)d_in[2];
  const float* Wh  = (const float*)d_in[3];
  const float* bh  = (const float*)d_in[4];
  const float* Wa  = (const float*)d_in[5];
  const float* ba  = (const float*)d_in[6];
  const float* Wb  = (const float*)d_in[7];
  const float* bb  = (const float*)d_in[8];
  const float* Wva = (const float*)d_in[9];
  const float* bva = (const float*)d_in[10];
  const float* Wvb = (const float*)d_in[11];
  const float* bvb = (const float*)d_in[12];

  float* outM = (float*)d_out;                          // 8192*256
  float* outH = (float*)d_out + (size_t)B_ROWS * MEMD;  // 8192*1024

  char* ws = (char*)d_ws;
  u16*   Abig = (u16*)(ws);                  // 8192*2304*2 = 37,748,736
  u16*   WhB  = (u16*)(ws + 37748736);       // 1024*2304*2 =  4,718,592
  u16*   hmB  = (u16*)(ws + 42467328);       // 8192*1280*2 = 20,971,520
  u16*   Wcat = (u16*)(ws + 63438848);       // 144*1280*2  =    368,640
  float* bcat = (float*)(ws + 63807488);     // 144*4

  k_cvt_xh  <<<dim3(2048), dim3(256), 0, stream>>>(x, h0, Abig);
  k_cvt_mem <<<dim3(1024), dim3(256), 0, stream>>>(mem, Abig, hmB);
  k_cvt_wh  <<<dim3(1152), dim3(256), 0, stream>>>(Wh, WhB);
  k_cvt_wcat<<<dim3(144),  dim3(256), 0, stream>>>(Wa, ba, Wb, bb, Wva, bva, Wvb, bvb, Wcat, bcat);
  k_gemm1   <<<dim3(512),  dim3(256), 0, stream>>>(Abig, WhB, bh, outH, hmB);
  k_gemm2   <<<dim3(512),  dim3(256), 0, stream>>>(hmB, Wcat, bcat, mem, outM);
}